// Round 9
// baseline (271.532 us; speedup 1.0000x reference)
//
#include <hip/hip_runtime.h>
#include <hip/hip_bf16.h>

// REN forward: BATCH=32768, N_X=64, N_UNITS=256, N_Y=32, N_U=64
typedef __attribute__((ext_vector_type(8))) short short8;
typedef __attribute__((ext_vector_type(4))) float floatx4;
typedef __attribute__((ext_vector_type(2))) float floatx2;

#define MFMA16 __builtin_amdgcn_mfma_f32_16x16x32_bf16

__device__ inline unsigned short bf16_rn(float f) {
    return (unsigned short)((__float_as_uint(f) + 0x8000u) >> 16);
}
__device__ inline short8 pack8(const float* v) {
    union { short8 s; unsigned int u[4]; } r;
#pragma unroll
    for (int j = 0; j < 4; j++) {
        union { __hip_bfloat162 h; unsigned int u; } c;
        c.h = __float22bfloat162_rn(make_float2(v[2 * j], v[2 * j + 1]));
        r.u[j] = c.u;
    }
    return r.s;
}

// ---------------------------------------------------------------------------
// Prep13: blocks 0..383 = lT1/t1/lT2/t2 (St staged in padded LDS, C2/D21
// column staged by 32 parallel lanes); blocks 384..799 = bf16 copies.
// ---------------------------------------------------------------------------
__global__ __launch_bounds__(64) void ren_prep13(
    const float* __restrict__ B2, const float* __restrict__ C2,
    const float* __restrict__ D12, const float* __restrict__ D21,
    const float* __restrict__ St, const float* __restrict__ Q,
    const float* __restrict__ Rinv,
    float* __restrict__ lT1, float* __restrict__ t1,
    float* __restrict__ lT2, float* __restrict__ t2,
    unsigned short* __restrict__ Wvb, unsigned short* __restrict__ C2b,
    unsigned short* __restrict__ D21b)
{
    const int t = threadIdx.x;
    const int blk = blockIdx.x;
    if (blk >= 384) {   // bf16-copy role (uniform branch)
        const int id = (blk - 384) * 64 + t;
        if (id < 16384) {
            Wvb[(id >> 6) * 128 + 64 + (id & 63)] = bf16_rn(D12[id]);
        } else if (id < 16384 + 2048) {
            C2b[id - 16384] = bf16_rn(C2[id - 16384]);
        } else if (id < 16384 + 2048 + 8192) {
            D21b[id - 18432] = bf16_rn(D21[id - 18432]);
        }
        return;
    }

    __shared__ float stl[64 * 33];  // St (64x32), padded
    __shared__ float colbuf[32];    // this block's C2/D21 column
    __shared__ float s1[64];

    const int r = blk;   // 0..383
    const int c = t;     // 0..63
#pragma unroll
    for (int j = 0; j < 32; j++) {
        const int id = j * 64 + t;
        stl[(id >> 5) * 33 + (id & 31)] = St[id];
    }
    if (t < 32)
        colbuf[t] = (r < 64) ? C2[t * 64 + r]
                  : (r < 320 ? D21[t * 256 + (r - 64)] : 0.f);
    __syncthreads();

    float v1;
    if (r < 64) {
        float s = 0.f;
#pragma unroll
        for (int p = 0; p < 32; p++) s += stl[c * 33 + p] * colbuf[p];
        v1 = s;
    } else if (r < 320) {
        float s = 0.f;
#pragma unroll
        for (int p = 0; p < 32; p++) s += stl[c * 33 + p] * colbuf[p];
        v1 = s - D12[(r - 64) * 64 + c];
    } else {
        v1 = B2[(r - 320) * 64 + c];
    }
    s1[c] = v1;
    lT1[r * 64 + c] = v1;
    if (c < 32) {
        const float v2 = (r < 320) ? colbuf[c] : 0.f;
        lT2[r * 32 + c] = v2;
    }
    __syncthreads();

    float a = 0.f;
#pragma unroll
    for (int k = 0; k < 64; k++) a += s1[k] * Rinv[k * 64 + c];
    t1[r * 64 + c] = a;

    if (c < 32) {
        float bq = 0.f;
#pragma unroll
        for (int k = 0; k < 32; k++) bq += colbuf[k] * Q[k * 32 + c];
        t2[r * 32 + c] = bq;
    }
}

// ---------------------------------------------------------------------------
// Prep 2: one H-row per block (256 x 320), LDS-staged X column, pipelined
// k-loop. Emits Wvb cols 0..63 (bf16), Drowsb (bf16, stored zeros),
// Dsup (fp32 pair-interleaved in-SUPERBLOCK 32x32 tiles:
//   Dsup[N*1024 + (q>>1)*64 + p*2 + (q&1)] = Drows[32N+q][32N+p]),
// lamg[i] = (2*log2e)*2/H22[i][i]  (pre-folded tanh scale).
// ---------------------------------------------------------------------------
__global__ __launch_bounds__(320) void ren_prep2(
    const float* __restrict__ X,
    const float* __restrict__ lT1, const float* __restrict__ t1,
    const float* __restrict__ lT2, const float* __restrict__ t2,
    unsigned short* __restrict__ Wvb, unsigned short* __restrict__ Drowsb,
    float* __restrict__ Dsup, float* __restrict__ lamg)
{
    __shared__ float xcol[384];
    const int c = threadIdx.x;     // 0..319
    const int i = blockIdx.x;      // 0..255 -> H row 64+i
    for (int t = c; t < 384; t += 320) xcol[t] = X[t * 384 + 64 + i];
    __syncthreads();

    float f0 = 0.f, f1 = 0.f, f2 = 0.f, f3 = 0.f;
    float ac[8], au[8], bc8[8], bu[8];
#pragma unroll
    for (int kk = 0; kk < 8; kk++) { ac[kk] = X[kk * 384 + c]; au[kk] = xcol[kk]; }
    for (int k0 = 0; k0 < 384; k0 += 16) {
#pragma unroll
        for (int kk = 0; kk < 8; kk++) {
            bc8[kk] = X[(k0 + 8 + kk) * 384 + c]; bu[kk] = xcol[k0 + 8 + kk];
        }
        f0 += au[0] * ac[0]; f1 += au[1] * ac[1];
        f2 += au[2] * ac[2]; f3 += au[3] * ac[3];
        f0 += au[4] * ac[4]; f1 += au[5] * ac[5];
        f2 += au[6] * ac[6]; f3 += au[7] * ac[7];
        if (k0 + 16 < 384) {
#pragma unroll
            for (int kk = 0; kk < 8; kk++) {
                ac[kk] = X[(k0 + 16 + kk) * 384 + c]; au[kk] = xcol[k0 + 16 + kk];
            }
        }
        f0 += bu[0] * bc8[0]; f1 += bu[1] * bc8[1];
        f2 += bu[2] * bc8[2]; f3 += bu[3] * bc8[3];
        f0 += bu[4] * bc8[4]; f1 += bu[5] * bc8[5];
        f2 += bu[6] * bc8[6]; f3 += bu[7] * bc8[7];
    }

    const float* __restrict__ t1r = t1 + (64 + i) * 64;
    const float* __restrict__ l1r = lT1 + c * 64;
#pragma unroll
    for (int m4 = 0; m4 < 16; m4++) {
        const float4 lv = *(const float4*)(l1r + m4 * 4);
        f0 += t1r[m4 * 4 + 0] * lv.x; f1 += t1r[m4 * 4 + 1] * lv.y;
        f2 += t1r[m4 * 4 + 2] * lv.z; f3 += t1r[m4 * 4 + 3] * lv.w;
    }
    const float* __restrict__ t2r = t2 + (64 + i) * 32;
    const float* __restrict__ l2r = lT2 + c * 32;
#pragma unroll
    for (int m4 = 0; m4 < 8; m4++) {
        const float4 lv = *(const float4*)(l2r + m4 * 4);
        f0 -= t2r[m4 * 4 + 0] * lv.x; f1 -= t2r[m4 * 4 + 1] * lv.y;
        f2 -= t2r[m4 * 4 + 2] * lv.z; f3 -= t2r[m4 * 4 + 3] * lv.w;
    }
    float acc = (f0 + f1) + (f2 + f3) + (((64 + i) == c) ? 0.001f : 0.f);

    if (c < 64) {
        Wvb[i * 128 + c] = bf16_rn(-acc);       // C_1 = -H_21
    } else {
        const int cb = c - 64;
        if (cb == i) lamg[i] = 5.7707801635558536f / acc;  // (2*log2e)*2/H22ii
        if (i == 0 && cb < 32) Dsup[cb * 2] = 0.f;  // zero unwritten row 0
        if (i < 255) {
            const float dv = (cb <= i - 1) ? -acc : 0.f;
            Drowsb[(i + 1) * 256 + cb] = bf16_rn(dv);
            const int row = i + 1;
            if ((cb >> 5) == (row >> 5)) {      // in-superblock 32x32, pair layout
                const int q = row & 31, p = cb & 31;
                Dsup[(row >> 5) * 1024 + (q >> 1) * 64 + p * 2 + (q & 1)] = dv;
            }
        } else {
            Drowsb[cb] = 0;
        }
    }
}

// ---------------------------------------------------------------------------
// Main: one wave per 16 batch rows. ACCUMULATOR-SCATTER dataflow:
// C-frag accumulators for all 8 superblocks (32 units each) live in
// registers; v-GEMM fills all upfront; per superblock N: transpose ->
// 32-wide pair triangle (fp32 Dsup tile in LDS) -> fold wf[N] -> scatter
// acc[M] += wf[N] @ Drows(M,N) for M>N. Only the M=N+1 MFMA is on the
// serial chain; all other loads/MFMAs float off the critical path.
// ---------------------------------------------------------------------------
__global__ __launch_bounds__(64) void ren_main(
    const float* __restrict__ u, const float* __restrict__ x0,
    const float* __restrict__ b,
    const unsigned short* __restrict__ Wvb,
    const unsigned short* __restrict__ Drowsb,
    const float* __restrict__ Dsup,
    const float* __restrict__ lamg,
    const unsigned short* __restrict__ C2b,
    const unsigned short* __restrict__ D21b,
    float* __restrict__ out)
{
    __shared__ float dblk[1024];      // current superblock 32x32 D (pair layout)
    __shared__ float tbuf[16][40];    // acc transpose: two 16-col tiles
    __shared__ float lamsh[256];
    __shared__ float bsh[256];

    const int L = threadIdx.x;
    const int col = L & 15;
    const int quad = L >> 4;
    const long row0 = (long)blockIdx.x * 16;

#pragma unroll
    for (int j = 0; j < 4; j++) {
        lamsh[j * 64 + L] = lamg[j * 64 + L];
        bsh[j * 64 + L]   = b[64 + j * 64 + L];
    }

    // z A-frags: 4 K-chunks of 32 over [x0 | u], batch row m=col
    short8 zf[4];
#pragma unroll
    for (int c = 0; c < 4; c++) {
        const float* p = (c < 2 ? x0 : u) + (row0 + col) * 64 + (c & 1) * 32 + quad * 8;
        float t[8];
        *(float4*)&t[0] = *(const float4*)p;
        *(float4*)&t[4] = *(const float4*)(p + 4);
        zf[c] = pack8(t);
    }

    // ---- v GEMM upfront into all 8 superblock accumulators ----
    floatx4 accA[8], accB[8];
#pragma unroll
    for (int N = 0; N < 8; N++) {
        floatx4 a = {0.f, 0.f, 0.f, 0.f}, bb = {0.f, 0.f, 0.f, 0.f};
#pragma unroll
        for (int c = 0; c < 4; c++) {
            const short8 fA = *(const short8*)(Wvb + (32 * N + col) * 128 + c * 32 + quad * 8);
            const short8 fB = *(const short8*)(Wvb + (32 * N + 16 + col) * 128 + c * 32 + quad * 8);
            a  = MFMA16(zf[c], fA, a, 0, 0, 0);
            bb = MFMA16(zf[c], fB, bb, 0, 0, 0);
        }
        accA[N] = a; accB[N] = bb;
    }

    short8 wf[8];
    const float4* Dsup4 = (const float4*)Dsup;

#pragma unroll
    for (int N = 0; N < 8; N++) {
        // ---- stage this superblock's 32x32 pair-D tile into LDS ----
        float4 dv0 = Dsup4[N * 256 + 0 * 64 + L];
        float4 dv1 = Dsup4[N * 256 + 1 * 64 + L];
        float4 dv2 = Dsup4[N * 256 + 2 * 64 + L];
        float4 dv3 = Dsup4[N * 256 + 3 * 64 + L];
        ((float4*)dblk)[0 * 64 + L] = dv0;
        ((float4*)dblk)[1 * 64 + L] = dv1;
        ((float4*)dblk)[2 * 64 + L] = dv2;
        ((float4*)dblk)[3 * 64 + L] = dv3;

        // ---- transpose acc (C-layout) + bias -> row layout via LDS ----
        const float bwA = bsh[32 * N + col];
        const float bwB = bsh[32 * N + 16 + col];
#pragma unroll
        for (int r = 0; r < 4; r++) {
            tbuf[quad * 4 + r][col]      = accA[N][r] + bwA;
            tbuf[quad * 4 + r][20 + col] = accB[N][r] + bwB;
        }
        float vl[32];
#pragma unroll
        for (int p4 = 0; p4 < 4; p4++) {
            *(float4*)&vl[p4 * 4]      = *(const float4*)&tbuf[col][p4 * 4];
            *(float4*)&vl[16 + p4 * 4] = *(const float4*)&tbuf[col][20 + p4 * 4];
        }

        // ---- 32-wide triangle in pairs (pk-fma), D broadcast from LDS ----
        float wl[32];
#pragma unroll
        for (int tq = 0; tq < 16; tq++) {
            floatx2 a2;
            a2[0] = vl[2 * tq]; a2[1] = vl[2 * tq + 1];
#pragma unroll
            for (int p4 = 0; p4 < tq; p4++) {
                const float4 d4 = *(const float4*)&dblk[tq * 64 + p4 * 4];
                floatx2 de; de[0] = d4.x; de[1] = d4.y;
                floatx2 dz; dz[0] = d4.z; dz[1] = d4.w;
                a2 += de * wl[2 * p4];
                a2 += dz * wl[2 * p4 + 1];
            }
            const float2 lmp = *(const float2*)&lamsh[32 * N + 2 * tq];
            floatx2 lm2; lm2[0] = lmp.x; lm2[1] = lmp.y;
            a2 *= lm2;
            const float e0 = __builtin_amdgcn_exp2f(a2[0]);
            const float e1 = __builtin_amdgcn_exp2f(a2[1]);
            wl[2 * tq]     = 1.f - 2.f * __builtin_amdgcn_rcpf(e0 + 1.f);
            wl[2 * tq + 1] = 1.f - 2.f * __builtin_amdgcn_rcpf(e1 + 1.f);
        }

        // ---- fold: A-frag chunk N (k = quad*8 + j, all 4 quads distinct) ----
        wf[N] = pack8(&wl[quad * 8]);

        // ---- scatter into future superblocks (M=N+1 first: critical) ----
#pragma unroll
        for (int M = N + 1; M < 8; M++) {
            const short8 hA = *(const short8*)(Drowsb + (32 * M + col) * 256 + N * 32 + quad * 8);
            const short8 hB = *(const short8*)(Drowsb + (32 * M + 16 + col) * 256 + N * 32 + quad * 8);
            accA[M] = MFMA16(wf[N], hA, accA[M], 0, 0, 0);
            accB[M] = MFMA16(wf[N], hB, accB[M], 0, 0, 0);
        }
    }

    // ---- y phase: Y[16][32] = x@C2^T + W@D21^T + b_y ----
    floatx4 y0 = {0.f, 0.f, 0.f, 0.f}, y1 = {0.f, 0.f, 0.f, 0.f};
#pragma unroll
    for (int c = 0; c < 2; c++) {
        const short8 b0 = *(const short8*)(C2b + col * 64 + c * 32 + quad * 8);
        const short8 b1 = *(const short8*)(C2b + (16 + col) * 64 + c * 32 + quad * 8);
        y0 = MFMA16(zf[c], b0, y0, 0, 0, 0);
        y1 = MFMA16(zf[c], b1, y1, 0, 0, 0);
    }
#pragma unroll
    for (int c = 0; c < 8; c++) {
        const short8 b0 = *(const short8*)(D21b + col * 256 + c * 32 + quad * 8);
        const short8 b1 = *(const short8*)(D21b + (16 + col) * 256 + c * 32 + quad * 8);
        y0 = MFMA16(wf[c], b0, y0, 0, 0, 0);
        y1 = MFMA16(wf[c], b1, y1, 0, 0, 0);
    }
    const float by0 = b[320 + col];
    const float by1 = b[336 + col];
#pragma unroll
    for (int r = 0; r < 4; r++) {
        out[(row0 + quad * 4 + r) * 32 + col]      = y0[r] + by0;
        out[(row0 + quad * 4 + r) * 32 + 16 + col] = y1[r] + by1;
    }
}

// ---------------------------------------------------------------------------
extern "C" void kernel_launch(void* const* d_in, const int* in_sizes, int n_in,
                              void* d_out, int out_size, void* d_ws, size_t ws_size,
                              hipStream_t stream)
{
    const float* u    = (const float*)d_in[0];
    const float* x0   = (const float*)d_in[1];
    const float* B2   = (const float*)d_in[2];
    const float* C2   = (const float*)d_in[3];
    const float* D12  = (const float*)d_in[4];
    const float* D21  = (const float*)d_in[5];
    const float* b    = (const float*)d_in[6];
    const float* X    = (const float*)d_in[7];
    // d_in[8] = Y1 (unused in forward)
    const float* St   = (const float*)d_in[9];
    const float* Q    = (const float*)d_in[10];
    const float* Rinv = (const float*)d_in[11];
    float* out = (float*)d_out;

    float* ws     = (float*)d_ws;
    float* lT1    = ws;                 // 384*64
    float* t1     = lT1 + 384 * 64;     // 384*64
    float* lT2    = t1 + 384 * 64;      // 384*32
    float* t2     = lT2 + 384 * 32;     // 384*32
    float* lamg   = t2 + 384 * 32;      // 256
    float* Dsup   = lamg + 256;         // 8*1024 fp32 (pair-interleaved 32x32)
    unsigned short* Drowsb = (unsigned short*)(Dsup + 8 * 1024); // 256*256
    unsigned short* Wvb    = Drowsb + 256 * 256;                 // 256*128
    unsigned short* C2b    = Wvb + 256 * 128;                    // 32*64
    unsigned short* D21b   = C2b + 32 * 64;                      // 32*256

    ren_prep13<<<dim3(800), dim3(64), 0, stream>>>(B2, C2, D12, D21, St, Q, Rinv,
                                                   lT1, t1, lT2, t2, Wvb, C2b, D21b);
    ren_prep2<<<dim3(256), dim3(320), 0, stream>>>(X, lT1, t1, lT2, t2,
                                                   Wvb, Drowsb, Dsup, lamg);

    const int batch = in_sizes[0] / 64;            // 32768
    ren_main<<<dim3(batch / 16), dim3(64), 0, stream>>>(u, x0, b, Wvb, Drowsb,
                                                        Dsup, lamg, C2b, D21b, out);
}

// Round 10
// 140.796 us; speedup vs baseline: 1.9285x; 1.9285x over previous
//
#include <hip/hip_runtime.h>
#include <hip/hip_bf16.h>

// REN forward: BATCH=32768, N_X=64, N_UNITS=256, N_Y=32, N_U=64
typedef __attribute__((ext_vector_type(8))) short short8;
typedef __attribute__((ext_vector_type(4))) float floatx4;
typedef __attribute__((ext_vector_type(2))) float floatx2;

#define MFMA16 __builtin_amdgcn_mfma_f32_16x16x32_bf16

__device__ inline unsigned short bf16_rn(float f) {
    return (unsigned short)((__float_as_uint(f) + 0x8000u) >> 16);
}
// Packed f32->bf16 via v_cvt_pk_bf16_f32 (RNE).
__device__ inline short8 pack8(const float* v) {
    union { short8 s; unsigned int u[4]; } r;
#pragma unroll
    for (int j = 0; j < 4; j++) {
        union { __hip_bfloat162 h; unsigned int u; } c;
        c.h = __float22bfloat162_rn(make_float2(v[2 * j], v[2 * j + 1]));
        r.u[j] = c.u;
    }
    return r.s;
}

// ---------------------------------------------------------------------------
// Prep13: blocks 0..383 = lT1/t1/lT2/t2 (St staged in padded LDS, C2/D21
// column staged by 32 parallel lanes); blocks 384..799 = bf16 copies.
// ---------------------------------------------------------------------------
__global__ __launch_bounds__(64) void ren_prep13(
    const float* __restrict__ B2, const float* __restrict__ C2,
    const float* __restrict__ D12, const float* __restrict__ D21,
    const float* __restrict__ St, const float* __restrict__ Q,
    const float* __restrict__ Rinv,
    float* __restrict__ lT1, float* __restrict__ t1,
    float* __restrict__ lT2, float* __restrict__ t2,
    unsigned short* __restrict__ Wvb, unsigned short* __restrict__ C2b,
    unsigned short* __restrict__ D21b)
{
    const int t = threadIdx.x;
    const int blk = blockIdx.x;
    if (blk >= 384) {   // bf16-copy role (uniform branch)
        const int id = (blk - 384) * 64 + t;
        if (id < 16384) {
            Wvb[(id >> 6) * 128 + 64 + (id & 63)] = bf16_rn(D12[id]);
        } else if (id < 16384 + 2048) {
            C2b[id - 16384] = bf16_rn(C2[id - 16384]);
        } else if (id < 16384 + 2048 + 8192) {
            D21b[id - 18432] = bf16_rn(D21[id - 18432]);
        }
        return;
    }

    __shared__ float stl[64 * 33];  // St (64x32), padded
    __shared__ float colbuf[32];    // this block's C2/D21 column
    __shared__ float s1[64];

    const int r = blk;   // 0..383
    const int c = t;     // 0..63
#pragma unroll
    for (int j = 0; j < 32; j++) {
        const int id = j * 64 + t;
        stl[(id >> 5) * 33 + (id & 31)] = St[id];
    }
    if (t < 32)
        colbuf[t] = (r < 64) ? C2[t * 64 + r]
                  : (r < 320 ? D21[t * 256 + (r - 64)] : 0.f);
    __syncthreads();

    float v1;
    if (r < 64) {
        float s = 0.f;
#pragma unroll
        for (int p = 0; p < 32; p++) s += stl[c * 33 + p] * colbuf[p];
        v1 = s;
    } else if (r < 320) {
        float s = 0.f;
#pragma unroll
        for (int p = 0; p < 32; p++) s += stl[c * 33 + p] * colbuf[p];
        v1 = s - D12[(r - 64) * 64 + c];
    } else {
        v1 = B2[(r - 320) * 64 + c];
    }
    s1[c] = v1;
    lT1[r * 64 + c] = v1;
    if (c < 32) {
        const float v2 = (r < 320) ? colbuf[c] : 0.f;
        lT2[r * 32 + c] = v2;
    }
    __syncthreads();

    float a = 0.f;
#pragma unroll
    for (int k = 0; k < 64; k++) a += s1[k] * Rinv[k * 64 + c];
    t1[r * 64 + c] = a;

    if (c < 32) {
        float bq = 0.f;
#pragma unroll
        for (int k = 0; k < 32; k++) bq += colbuf[k] * Q[k * 32 + c];
        t2[r * 32 + c] = bq;
    }
}

// ---------------------------------------------------------------------------
// Prep 2: one H-row per block (256 x 320), LDS-staged X column, pipelined
// k-loop. Emits Wvb cols 0..63 (bf16), Drowsb (bf16, stored zeros),
// Dpair (fp32 pair-interleaved diagonal 16x16 blocks), lamg (tanh scale).
// ---------------------------------------------------------------------------
__global__ __launch_bounds__(320) void ren_prep2(
    const float* __restrict__ X,
    const float* __restrict__ lT1, const float* __restrict__ t1,
    const float* __restrict__ lT2, const float* __restrict__ t2,
    unsigned short* __restrict__ Wvb, unsigned short* __restrict__ Drowsb,
    float* __restrict__ Dpair, float* __restrict__ lamg)
{
    __shared__ float xcol[384];
    const int c = threadIdx.x;     // 0..319
    const int i = blockIdx.x;      // 0..255 -> H row 64+i
    for (int t = c; t < 384; t += 320) xcol[t] = X[t * 384 + 64 + i];
    __syncthreads();

    float f0 = 0.f, f1 = 0.f, f2 = 0.f, f3 = 0.f;
    float ac[8], au[8], bc8[8], bu[8];
#pragma unroll
    for (int kk = 0; kk < 8; kk++) { ac[kk] = X[kk * 384 + c]; au[kk] = xcol[kk]; }
    for (int k0 = 0; k0 < 384; k0 += 16) {
#pragma unroll
        for (int kk = 0; kk < 8; kk++) {
            bc8[kk] = X[(k0 + 8 + kk) * 384 + c]; bu[kk] = xcol[k0 + 8 + kk];
        }
        f0 += au[0] * ac[0]; f1 += au[1] * ac[1];
        f2 += au[2] * ac[2]; f3 += au[3] * ac[3];
        f0 += au[4] * ac[4]; f1 += au[5] * ac[5];
        f2 += au[6] * ac[6]; f3 += au[7] * ac[7];
        if (k0 + 16 < 384) {
#pragma unroll
            for (int kk = 0; kk < 8; kk++) {
                ac[kk] = X[(k0 + 16 + kk) * 384 + c]; au[kk] = xcol[k0 + 16 + kk];
            }
        }
        f0 += bu[0] * bc8[0]; f1 += bu[1] * bc8[1];
        f2 += bu[2] * bc8[2]; f3 += bu[3] * bc8[3];
        f0 += bu[4] * bc8[4]; f1 += bu[5] * bc8[5];
        f2 += bu[6] * bc8[6]; f3 += bu[7] * bc8[7];
    }

    const float* __restrict__ t1r = t1 + (64 + i) * 64;
    const float* __restrict__ l1r = lT1 + c * 64;
#pragma unroll
    for (int m4 = 0; m4 < 16; m4++) {
        const float4 lv = *(const float4*)(l1r + m4 * 4);
        f0 += t1r[m4 * 4 + 0] * lv.x; f1 += t1r[m4 * 4 + 1] * lv.y;
        f2 += t1r[m4 * 4 + 2] * lv.z; f3 += t1r[m4 * 4 + 3] * lv.w;
    }
    const float* __restrict__ t2r = t2 + (64 + i) * 32;
    const float* __restrict__ l2r = lT2 + c * 32;
#pragma unroll
    for (int m4 = 0; m4 < 8; m4++) {
        const float4 lv = *(const float4*)(l2r + m4 * 4);
        f0 -= t2r[m4 * 4 + 0] * lv.x; f1 -= t2r[m4 * 4 + 1] * lv.y;
        f2 -= t2r[m4 * 4 + 2] * lv.z; f3 -= t2r[m4 * 4 + 3] * lv.w;
    }
    float acc = (f0 + f1) + (f2 + f3) + (((64 + i) == c) ? 0.001f : 0.f);

    if (c < 64) {
        Wvb[i * 128 + c] = bf16_rn(-acc);       // C_1 = -H_21
    } else {
        const int cb = c - 64;
        if (cb == i) lamg[i] = 5.7707801635558536f / acc;  // (2*log2e)*2/H22ii
        if (i < 255) {
            const float dv = (cb <= i - 1) ? -acc : 0.f;
            Drowsb[(i + 1) * 256 + cb] = bf16_rn(dv);
            const int row = i + 1;
            if ((row >> 4) == (cb >> 4)) {      // diagonal 16-block, pair layout
                const int q = row & 15, p = cb & 15;
                Dpair[(row >> 4) * 256 + (q >> 1) * 32 + p * 2 + (q & 1)] = dv;
            }
        } else {
            Drowsb[cb] = 0;
        }
    }
}

// ---------------------------------------------------------------------------
// Main: rotated pipeline (R7 structure). KEY CHANGE: __launch_bounds__(64,2)
// — grid supplies only 2 waves/SIMD, so let regalloc use up to ~256 VGPRs;
// this is what allows the same-iteration prefetch (vfN/hfN live across the
// triangle) to survive instead of being sunk to its uses (R5/R7: VGPR 88-92).
// ---------------------------------------------------------------------------
__global__ __launch_bounds__(64, 2) void ren_main(
    const float* __restrict__ u, const float* __restrict__ x0,
    const float* __restrict__ b,
    const unsigned short* __restrict__ Wvb,
    const unsigned short* __restrict__ Drowsb,
    const float* __restrict__ Dpair,
    const float* __restrict__ lamg,
    const unsigned short* __restrict__ C2b,
    const unsigned short* __restrict__ D21b,
    float* __restrict__ out)
{
    __shared__ float buf[2][16][20];  // acc transpose (stride 20 -> 2-way max)
    __shared__ float dblk[2][256];    // pair-interleaved 16x16 D tiles
    __shared__ float lamsh[256];
    __shared__ float bsh[256];

    const int L = threadIdx.x;
    const int col = L & 15;
    const int quad = L >> 4;
    const int row0 = blockIdx.x * 16;

#pragma unroll
    for (int j = 0; j < 4; j++) {
        lamsh[j * 64 + L] = lamg[j * 64 + L];
        bsh[j * 64 + L]   = b[64 + j * 64 + L];
    }

    // z A-frags: 4 K-chunks of 32 over [x0 | u], batch row m=col
    short8 zf[4];
#pragma unroll
    for (int c = 0; c < 4; c++) {
        const float* p = (c < 2 ? x0 : u) + (long)(row0 + col) * 64 + (c & 1) * 32 + quad * 8;
        float t[8];
        *(float4*)&t[0] = *(const float4*)p;
        *(float4*)&t[4] = *(const float4*)(p + 4);
        zf[c] = pack8(t);
    }

    const short8 zero8 = {0, 0, 0, 0, 0, 0, 0, 0};
    short8 wf[8];
#pragma unroll
    for (int c = 0; c < 8; c++) wf[c] = zero8;

    // ---- pre-loop: acc for block 0 (v-GEMM only), D tile 0 ----
    float4 dcur = *(const float4*)(Dpair + 4 * L);
    floatx4 acc0 = {0.f, 0.f, 0.f, 0.f}, acc1 = {0.f, 0.f, 0.f, 0.f};
    {
        short8 v0 = *(const short8*)(Wvb + col * 128 + quad * 8);
        short8 v1 = *(const short8*)(Wvb + col * 128 + 32 + quad * 8);
        short8 v2 = *(const short8*)(Wvb + col * 128 + 64 + quad * 8);
        short8 v3 = *(const short8*)(Wvb + col * 128 + 96 + quad * 8);
        acc0 = MFMA16(zf[0], v0, acc0, 0, 0, 0);
        acc1 = MFMA16(zf[1], v1, acc1, 0, 0, 0);
        acc0 = MFMA16(zf[2], v2, acc0, 0, 0, 0);
        acc1 = MFMA16(zf[3], v3, acc1, 0, 0, 0);
    }

    short8 yc[4];

#pragma unroll
    for (int n = 0; n < 16; n++) {
        const int pp = n & 1;

        // ---- (1) same-iteration prefetch of block-(n+1) operands ----
        short8 vfN[4], hfN[8];
        float4 dnxt;
        if (n < 15) {
            dnxt = *(const float4*)(Dpair + (n + 1) * 256 + 4 * L);
#pragma unroll
            for (int c = 0; c < 4; c++)
                vfN[c] = *(const short8*)(Wvb + (16 * (n + 1) + col) * 128 + c * 32 + quad * 8);
#pragma unroll
            for (int c = 0; c < 8; c++)
                if (c < ((n + 2) >> 1))
                    hfN[c] = *(const short8*)(Drowsb + (16 * (n + 1) + col) * 256 + c * 32 + quad * 8);
        } else {
            yc[0] = *(const short8*)(C2b + col * 64 + quad * 8);
            yc[1] = *(const short8*)(C2b + col * 64 + 32 + quad * 8);
            yc[2] = *(const short8*)(C2b + (16 + col) * 64 + quad * 8);
            yc[3] = *(const short8*)(C2b + (16 + col) * 64 + 32 + quad * 8);
        }

        // ---- (2) stage current D tile; transpose acc+bias via LDS ----
        *(float4*)&dblk[pp][4 * L] = dcur;
        const float bwv = bsh[16 * n + col];
#pragma unroll
        for (int r = 0; r < 4; r++)
            buf[pp][quad * 4 + r][col] = acc0[r] + acc1[r] + bwv;

        float vl[16];
#pragma unroll
        for (int p4 = 0; p4 < 4; p4++)
            *(float4*)&vl[p4 * 4] = *(const float4*)&buf[pp][col][p4 * 4];

        // ---- (3) triangle in pairs (pk-fma), D broadcast from LDS ----
        float wl[16];
#pragma unroll
        for (int tq = 0; tq < 8; tq++) {
            floatx2 a2;
            a2[0] = vl[2 * tq]; a2[1] = vl[2 * tq + 1];
#pragma unroll
            for (int p4 = 0; p4 < tq; p4++) {
                const float4 d4 = *(const float4*)&dblk[pp][tq * 32 + p4 * 4];
                floatx2 de; de[0] = d4.x; de[1] = d4.y;
                floatx2 dz; dz[0] = d4.z; dz[1] = d4.w;
                a2 += de * wl[2 * p4];
                a2 += dz * wl[2 * p4 + 1];
            }
            const float2 lmp = *(const float2*)&lamsh[16 * n + 2 * tq];
            floatx2 lm2; lm2[0] = lmp.x; lm2[1] = lmp.y;
            a2 *= lm2;
            const float e0 = __builtin_amdgcn_exp2f(a2[0]);
            const float e1 = __builtin_amdgcn_exp2f(a2[1]);
            wl[2 * tq]     = 1.f - 2.f * __builtin_amdgcn_rcpf(e0 + 1.f);
            wl[2 * tq + 1] = 1.f - 2.f * __builtin_amdgcn_rcpf(e1 + 1.f);
        }

        // ---- (4) fold w block into A-frag chunk ----
        {
            const short8 nf = pack8(&wl[(quad & 1) * 8]);
            const int cc = n >> 1;
            if ((n & 1) == 0) wf[cc] = (quad < 2) ? nf : zero8;
            else if (quad >= 2) wf[cc] = nf;
        }

        // ---- (5) MFMA phase for block n+1 (prefetched operands hot) ----
        if (n < 15) {
            floatx4 a0 = {0.f, 0.f, 0.f, 0.f}, a1 = {0.f, 0.f, 0.f, 0.f};
            a0 = MFMA16(zf[0], vfN[0], a0, 0, 0, 0);
            a1 = MFMA16(zf[1], vfN[1], a1, 0, 0, 0);
            a0 = MFMA16(zf[2], vfN[2], a0, 0, 0, 0);
            a1 = MFMA16(zf[3], vfN[3], a1, 0, 0, 0);
#pragma unroll
            for (int c = 0; c < 8; c++)
                if (c < ((n + 2) >> 1)) {
                    if (c & 1) a1 = MFMA16(wf[c], hfN[c], a1, 0, 0, 0);
                    else       a0 = MFMA16(wf[c], hfN[c], a0, 0, 0, 0);
                }
            acc0 = a0; acc1 = a1;
            dcur = dnxt;
        }
    }

    // ---- y phase: Y[16][32] = x@C2^T + W@D21^T + b_y ----
    floatx4 y0 = {0.f, 0.f, 0.f, 0.f}, y1 = {0.f, 0.f, 0.f, 0.f};
    y0 = MFMA16(zf[0], yc[0], y0, 0, 0, 0);
    y1 = MFMA16(zf[0], yc[2], y1, 0, 0, 0);
    y0 = MFMA16(zf[1], yc[1], y0, 0, 0, 0);
    y1 = MFMA16(zf[1], yc[3], y1, 0, 0, 0);
#pragma unroll
    for (int c = 0; c < 8; c++) {
        const short8 b0 = *(const short8*)(D21b + col * 256 + c * 32 + quad * 8);
        const short8 b1 = *(const short8*)(D21b + (16 + col) * 256 + c * 32 + quad * 8);
        y0 = MFMA16(wf[c], b0, y0, 0, 0, 0);
        y1 = MFMA16(wf[c], b1, y1, 0, 0, 0);
    }
    const float by0 = b[320 + col];
    const float by1 = b[336 + col];
#pragma unroll
    for (int r = 0; r < 4; r++) {
        out[(long)(row0 + quad * 4 + r) * 32 + col]      = y0[r] + by0;
        out[(long)(row0 + quad * 4 + r) * 32 + 16 + col] = y1[r] + by1;
    }
}

// ---------------------------------------------------------------------------
extern "C" void kernel_launch(void* const* d_in, const int* in_sizes, int n_in,
                              void* d_out, int out_size, void* d_ws, size_t ws_size,
                              hipStream_t stream)
{
    const float* u    = (const float*)d_in[0];
    const float* x0   = (const float*)d_in[1];
    const float* B2   = (const float*)d_in[2];
    const float* C2   = (const float*)d_in[3];
    const float* D12  = (const float*)d_in[4];
    const float* D21  = (const float*)d_in[5];
    const float* b    = (const float*)d_in[6];
    const float* X    = (const float*)d_in[7];
    // d_in[8] = Y1 (unused in forward)
    const float* St   = (const float*)d_in[9];
    const float* Q    = (const float*)d_in[10];
    const float* Rinv = (const float*)d_in[11];
    float* out = (float*)d_out;

    float* ws     = (float*)d_ws;
    float* lT1    = ws;                 // 384*64
    float* t1     = lT1 + 384 * 64;     // 384*64
    float* lT2    = t1 + 384 * 64;      // 384*32
    float* t2     = lT2 + 384 * 32;     // 384*32
    float* lamg   = t2 + 384 * 32;      // 256
    float* Dpair  = lamg + 256;         // 16*256 fp32 (pair-interleaved)
    unsigned short* Drowsb = (unsigned short*)(Dpair + 16 * 256); // 256*256
    unsigned short* Wvb    = Drowsb + 256 * 256;                  // 256*128
    unsigned short* C2b    = Wvb + 256 * 128;                     // 32*64
    unsigned short* D21b   = C2b + 32 * 64;                       // 32*256

    ren_prep13<<<dim3(800), dim3(64), 0, stream>>>(B2, C2, D12, D21, St, Q, Rinv,
                                                   lT1, t1, lT2, t2, Wvb, C2b, D21b);
    ren_prep2<<<dim3(256), dim3(320), 0, stream>>>(X, lT1, t1, lT2, t2,
                                                   Wvb, Drowsb, Dpair, lamg);

    const int batch = in_sizes[0] / 64;            // 32768
    ren_main<<<dim3(batch / 16), dim3(64), 0, stream>>>(u, x0, b, Wvb, Drowsb,
                                                        Dpair, lamg, C2b, D21b, out);
}